// Round 1
// baseline (4012.826 us; speedup 1.0000x reference)
//
#include <hip/hip_runtime.h>
#include <stdint.h>

#define BB 64
#define LL 512
#define UU 7
#define HH 128
#define G4H 512
#define NN (BB*UU)       // 448
#define PREDN 96
#define NBLK 224
#define NB 2

// ws layout (float offsets)
#define OFF_MEAN 0
#define OFF_STD  448
#define OFF_A    896
#define OFF_B0   1408
#define OFF_B1   1920
#define OFF_H1   2432              // 448*128 floats
#define OFF_XS   59776             // 448*512 floats

__device__ __forceinline__ float bflo(uint32_t w){ union{uint32_t u; float f;} v; v.u = w<<16; return v.f; }
__device__ __forceinline__ float bfhi(uint32_t w){ union{uint32_t u; float f;} v; v.u = w & 0xffff0000u; return v.f; }

static __device__ __forceinline__ uint32_t packbf2(float a, float b){
    union { float f; uint32_t u; } ua, ub; ua.f = a; ub.f = b;
    uint32_t x = ua.u, y = ub.u;
    uint32_t lo = (x + 0x7fffu + ((x>>16)&1u)) >> 16;
    uint32_t hi = (y + 0x7fffu + ((y>>16)&1u)) >> 16;
    return (lo & 0xffffu) | (hi<<16);
}

__device__ __forceinline__ float sigf(float x){
    return __fdividef(1.f, 1.f + __expf(-x));
}
__device__ __forceinline__ float tanh_fast(float x){
    float e = __expf(2.f*x);
    return 1.f - __fdividef(2.f, e + 1.f);
}

__device__ __forceinline__ void unpack8(const uint32_t* w, float* o){
    o[0]=bflo(w[0]); o[1]=bfhi(w[0]);
    o[2]=bflo(w[1]); o[3]=bfhi(w[1]);
    o[4]=bflo(w[2]); o[5]=bfhi(w[2]);
    o[6]=bflo(w[3]); o[7]=bfhi(w[3]);
}
__device__ __forceinline__ float dot8(const float* w, float4 a, float4 b){
    return w[0]*a.x + w[1]*a.y + w[2]*a.z + w[3]*a.w
         + w[4]*b.x + w[5]*b.y + w[6]*b.z + w[7]*b.w;
}

// ---------------- K1: per-(b,u) mean/std over time ----------------
__global__ void stats_k(const float* __restrict__ x, float* __restrict__ ws){
    int bu = blockIdx.x;            // 0..447
    int b = bu / 7, u = bu % 7;
    int i = threadIdx.x;            // 0..63 (one wave)
    const float* p = x + b*3584 + u;
    float s = 0.f, q = 0.f;
    #pragma unroll
    for (int m=0;m<8;m++){ float v = p[(i + 64*m)*7]; s += v; q += v*v; }
    for (int o=32;o>0;o>>=1){ s += __shfl_down(s,o); q += __shfl_down(q,o); }
    if (i==0){
        float mean = s * (1.f/512.f);
        float var  = q * (1.f/512.f) - mean*mean;
        ws[OFF_MEAN + bu] = mean;
        ws[OFF_STD  + bu] = sqrtf(var + 1e-5f);
    }
}

// ---------------- K2: normalize (raw-reshape flat copy) ----------------
__global__ void norm_k(const float* __restrict__ x, float* __restrict__ ws){
    int i = blockIdx.x*256 + threadIdx.x;   // < 229376 exactly (896*256)
    int b = i / 3584, u = i % 7;            // 3584 % 7 == 0, so i%7 is the channel
    float m = ws[OFF_MEAN + b*7 + u];
    float sd = ws[OFF_STD + b*7 + u];
    ws[OFF_XS + i] = (x[i] - m) / sd;
}

// ---------------- K3: A = Wih0@embW, B0, B1 ----------------
__global__ void prep_k(const float* __restrict__ Wih, const float* __restrict__ embW,
                       const float* __restrict__ embb, const float* __restrict__ bih,
                       const float* __restrict__ bhh, float* __restrict__ ws){
    int g = threadIdx.x;            // 0..511
    const float* wr = Wih + g*HH;   // layer 0 row
    float a = 0.f, bb = 0.f;
    #pragma unroll 4
    for (int k=0;k<HH;k++){ a += wr[k]*embW[k]; bb += wr[k]*embb[k]; }
    ws[OFF_A  + g] = a;
    ws[OFF_B0 + g] = bb + bih[g] + bhh[g];
    ws[OFF_B1 + g] = bih[512 + g] + bhh[512 + g];
}

// ---------------- K4: fused 2-layer persistent LSTM ----------------
__global__ __launch_bounds__(512, 2) void lstm_fused(
    const float* __restrict__ Whh,    // [2,512,128]
    const float* __restrict__ Wih,    // [2,512,128]
    float* __restrict__ ws)
{
    __shared__ __align__(16) uint16_t wih1[G4H*HH];           // bf16, 128 KB, swizzled
    __shared__ __align__(16) float h0s[NB*HH], h1s[NB*HH];
    __shared__ __align__(16) float g0s[NB*G4H], g1s[NB*G4H];
    __shared__ __align__(16) float xsl[NB*LL];

    const int tid = threadIdx.x;
    const int g   = tid;                   // gate row this thread owns
    const int n0  = blockIdx.x * NB;

    // --- weights for Whh0 / Whh1 rows into registers (packed bf16) ---
    uint32_t w0[64], w1[64];
    {
        const float4* p0 = (const float4*)(Whh + (size_t)g*HH);
        const float4* p1 = (const float4*)(Whh + 65536 + (size_t)g*HH);
        #pragma unroll
        for (int c=0;c<32;c++){
            float4 v = p0[c];
            w0[2*c]   = packbf2(v.x, v.y);
            w0[2*c+1] = packbf2(v.z, v.w);
        }
        #pragma unroll
        for (int c=0;c<32;c++){
            float4 v = p1[c];
            w1[2*c]   = packbf2(v.x, v.y);
            w1[2*c+1] = packbf2(v.z, v.w);
        }
    }
    // --- stage Wih1 -> LDS bf16, XOR-swizzled 16B chunks ---
    for (int idx = tid; idx < G4H*HH; idx += 512){
        int row = idx >> 7, k = idx & 127;
        int c = k >> 3, j = k & 7;
        float v = Wih[65536 + idx];
        wih1[row*128 + ((c ^ (row&7))<<3) + j] = (uint16_t)(packbf2(v, 0.f) & 0xffffu);
    }
    // --- stage this block's xs rows ---
    for (int idx = tid; idx < NB*LL; idx += 512){
        xsl[idx] = ws[OFF_XS + (n0 + (idx>>9))*LL + (idx & 511)];
    }
    if (tid < NB*HH){ h0s[tid] = 0.f; h1s[tid] = 0.f; }
    const float a_g  = ws[OFF_A  + g];
    const float b0_g = ws[OFF_B0 + g];
    const float b1_g = ws[OFF_B1 + g];
    float c0 = 0.f, c1 = 0.f;
    __syncthreads();

    const float4* h0q = (const float4*)h0s;   // [NB*32]
    const float4* h1q = (const float4*)h1s;
    const uint4*  W4  = (const uint4*)wih1;
    const int swz   = g & 7;
    const int wbase = g*16;

    for (int t=0; t<LL; ++t){
        // ---- phase A: layer-0 gate preactivations ----
        {
            float acc0 = xsl[t]       * a_g + b0_g;
            float acc1 = xsl[512 + t] * a_g + b0_g;
            #pragma unroll
            for (int c=0;c<16;c++){
                float wv[8]; unpack8(&w0[4*c], wv);
                acc0 += dot8(wv, h0q[2*c],      h0q[2*c+1]);
                acc1 += dot8(wv, h0q[32 + 2*c], h0q[32 + 2*c+1]);
            }
            g0s[g] = acc0; g0s[512 + g] = acc1;
        }
        __syncthreads();
        // ---- phase B: layer-0 elementwise (c,h update) ----
        if (tid < 256){
            int nn = tid >> 7, j = tid & 127;
            float i_ = sigf(g0s[nn*512 + j]);
            float f_ = sigf(g0s[nn*512 + j + 128]);
            float gg = tanh_fast(g0s[nn*512 + j + 256]);
            float o_ = sigf(g0s[nn*512 + j + 384]);
            c0 = f_*c0 + i_*gg;
            h0s[nn*128 + j] = o_ * tanh_fast(c0);
        }
        __syncthreads();
        // ---- phase C: layer-1 gate preactivations (Wih1 from LDS + Whh1 regs) ----
        {
            float acc0 = b1_g, acc1 = b1_g;
            #pragma unroll
            for (int c=0;c<16;c++){
                uint4 wc = W4[wbase + (c ^ swz)];
                float wi[8];
                wi[0]=bflo(wc.x); wi[1]=bfhi(wc.x);
                wi[2]=bflo(wc.y); wi[3]=bfhi(wc.y);
                wi[4]=bflo(wc.z); wi[5]=bfhi(wc.z);
                wi[6]=bflo(wc.w); wi[7]=bfhi(wc.w);
                float vv[8]; unpack8(&w1[4*c], vv);
                float4 a0=h0q[2*c], a1=h0q[2*c+1], a2=h0q[32+2*c], a3=h0q[32+2*c+1];
                float4 p0=h1q[2*c], p1=h1q[2*c+1], p2=h1q[32+2*c], p3=h1q[32+2*c+1];
                acc0 += dot8(wi, a0, a1) + dot8(vv, p0, p1);
                acc1 += dot8(wi, a2, a3) + dot8(vv, p2, p3);
            }
            g1s[g] = acc0; g1s[512 + g] = acc1;
        }
        __syncthreads();
        // ---- phase D: layer-1 elementwise ----
        if (tid < 256){
            int nn = tid >> 7, j = tid & 127;
            float i_ = sigf(g1s[nn*512 + j]);
            float f_ = sigf(g1s[nn*512 + j + 128]);
            float gg = tanh_fast(g1s[nn*512 + j + 256]);
            float o_ = sigf(g1s[nn*512 + j + 384]);
            c1 = f_*c1 + i_*gg;
            h1s[nn*128 + j] = o_ * tanh_fast(c1);
        }
        __syncthreads();
    }
    if (tid < 256){
        ws[OFF_H1 + n0*HH + tid] = h1s[tid];
    }
}

// ---------------- K5: FC head + de-normalization ----------------
__global__ void out_k(const float* __restrict__ fcW, const float* __restrict__ fcb,
                      const float* __restrict__ ws, float* __restrict__ out){
    __shared__ float hl[128];
    int n = blockIdx.x, tid = threadIdx.x;    // block=128
    hl[tid] = ws[OFF_H1 + n*128 + tid];
    __syncthreads();
    if (tid < PREDN){
        float acc = fcb[tid];
        const float* wr = fcW + tid*128;
        #pragma unroll 4
        for (int k=0;k<128;k++) acc += wr[k]*hl[k];
        int idx = n*PREDN + tid;
        int b = idx / 672, u = idx % 7;
        out[idx] = acc * ws[OFF_STD + b*7 + u] + ws[OFF_MEAN + b*7 + u];
    }
}

extern "C" void kernel_launch(void* const* d_in, const int* in_sizes, int n_in,
                              void* d_out, int out_size, void* d_ws, size_t ws_size,
                              hipStream_t stream)
{
    const float* x    = (const float*)d_in[0];
    const float* embW = (const float*)d_in[1];
    const float* embb = (const float*)d_in[2];
    const float* Wih  = (const float*)d_in[3];
    const float* Whh  = (const float*)d_in[4];
    const float* bih  = (const float*)d_in[5];
    const float* bhh  = (const float*)d_in[6];
    const float* fcW  = (const float*)d_in[7];
    const float* fcb  = (const float*)d_in[8];
    float* ws  = (float*)d_ws;
    float* out = (float*)d_out;

    stats_k<<<448, 64, 0, stream>>>(x, ws);
    norm_k<<<896, 256, 0, stream>>>(x, ws);
    prep_k<<<1, 512, 0, stream>>>(Wih, embW, embb, bih, bhh, ws);
    lstm_fused<<<NBLK, 512, 0, stream>>>(Whh, Wih, ws);
    out_k<<<NN, 128, 0, stream>>>(fcW, fcb, ws, out);
}

// Round 3
// 2007.034 us; speedup vs baseline: 1.9994x; 1.9994x over previous
//
#include <hip/hip_runtime.h>
#include <stdint.h>

typedef short bf16x8 __attribute__((ext_vector_type(8)));
typedef float f32x4  __attribute__((ext_vector_type(4)));
typedef unsigned int uint2v __attribute__((ext_vector_type(2)));

#define BB 64
#define LL 512
#define HH 128
#define NN 448
#define PREDN 96

// ws layout (float offsets)
#define OFF_MEAN 0
#define OFF_STD  448
#define OFF_A    896
#define OFF_B0   1408
#define OFF_B1   1920
#define OFF_H1   2432              // 448*128 floats
#define OFF_XST  59776             // 28 blocks * 512 t * 16 seq

__device__ __forceinline__ float bflo(uint32_t w){ union{uint32_t u; float f;} v; v.u = w<<16; return v.f; }
__device__ __forceinline__ float bfhi(uint32_t w){ union{uint32_t u; float f;} v; v.u = w & 0xffff0000u; return v.f; }

static __device__ __forceinline__ uint32_t packbf2(float a, float b){
    union { float f; uint32_t u; } ua, ub; ua.f = a; ub.f = b;
    uint32_t x = ua.u, y = ub.u;
    uint32_t lo = (x + 0x7fffu + ((x>>16)&1u)) >> 16;
    uint32_t hi = (y + 0x7fffu + ((y>>16)&1u)) >> 16;
    return (lo & 0xffffu) | (hi<<16);
}

__device__ __forceinline__ float sigf(float x){
    return __fdividef(1.f, 1.f + __expf(-x));
}
__device__ __forceinline__ float tanh_fast(float x){
    float e = __expf(2.f*x);
    return 1.f - __fdividef(2.f, e + 1.f);
}

// ---------------- K1: per-(b,u) mean/std over time ----------------
__global__ void stats_k(const float* __restrict__ x, float* __restrict__ ws){
    int bu = blockIdx.x;            // 0..447
    int b = bu / 7, u = bu % 7;
    int i = threadIdx.x;            // one wave
    const float* p = x + b*3584 + u;
    float s = 0.f, q = 0.f;
    #pragma unroll
    for (int m=0;m<8;m++){ float v = p[(i + 64*m)*7]; s += v; q += v*v; }
    for (int o=32;o>0;o>>=1){ s += __shfl_down(s,o); q += __shfl_down(q,o); }
    if (i==0){
        float mean = s * (1.f/512.f);
        float var  = q * (1.f/512.f) - mean*mean;
        ws[OFF_MEAN + bu] = mean;
        ws[OFF_STD  + bu] = sqrtf(var + 1e-5f);
    }
}

// ---------------- K2: normalize + write transposed [blk][t][16] ----------------
__global__ void norm_k(const float* __restrict__ x, float* __restrict__ ws){
    int i = blockIdx.x*256 + threadIdx.x;   // < 229376 exactly
    int b = i / 3584, u = i % 7;            // 3584 % 7 == 0
    float m = ws[OFF_MEAN + b*7 + u];
    float sd = ws[OFF_STD + b*7 + u];
    float v = (x[i] - m) / sd;
    int np = i >> 9, tp = i & 511;          // raw-reshape row/col
    ws[OFF_XST + (np>>4)*8192 + tp*16 + (np&15)] = v;
}

// ---------------- K3: A' = Wih0@embW, B0', B1' (orig gate order) ----------------
__global__ void prep_k(const float* __restrict__ Wih, const float* __restrict__ embW,
                       const float* __restrict__ embb, const float* __restrict__ bih,
                       const float* __restrict__ bhh, float* __restrict__ ws){
    int g = threadIdx.x;            // 0..511
    const float* wr = Wih + g*HH;
    float a = 0.f, bb = 0.f;
    #pragma unroll 4
    for (int k=0;k<HH;k++){ a += wr[k]*embW[k]; bb += wr[k]*embb[k]; }
    ws[OFF_A  + g] = a;
    ws[OFF_B0 + g] = bb + bih[g] + bhh[g];
    ws[OFF_B1 + g] = bih[512 + g] + bhh[512 + g];
}

// ---------------- K4: persistent MFMA LSTM, 28 blocks x 16 seq ----------------
// h0 buffer: 160 rows x 16 seq (rows 0..127 = h0, 128 = xs, 129 = const 1,
// 130..159 = zero padding so the kk=4 fragment's TRD2 reads zeros, never OOB)
#define H0ROWS 160
#define H0ELE (H0ROWS*16)   // 2560 elems per buffer
#define H1ELE (128*16)      // 2048

union FragU { bf16x8 v; uint2v p[2]; uint32_t u4[4]; };

__device__ __forceinline__ f32x4 mm(bf16x8 a, bf16x8 b, f32x4 c){
    return __builtin_amdgcn_mfma_f32_16x16x32_bf16(a, b, c, 0, 0, 0);
}

__device__ __forceinline__ bf16x8 load_frag(const float* __restrict__ row, int k0){
    float4 lo = *(const float4*)(row + k0);
    float4 hi = *(const float4*)(row + k0 + 16);
    FragU r;
    r.u4[0] = packbf2(lo.x, lo.y);
    r.u4[1] = packbf2(lo.z, lo.w);
    r.u4[2] = packbf2(hi.x, hi.y);
    r.u4[3] = packbf2(hi.z, hi.w);
    return r.v;
}

#define TRD(d, b, off)  asm volatile("ds_read_b64_tr_b16 %0, %1" : "=v"(d) : "v"((unsigned)((b)+(off))))
#define TRD2(d, b, off) asm volatile("ds_read_b64_tr_b16 %0, %1 offset:512" : "=v"(d) : "v"((unsigned)((b)+(off))))
#define LGKM2 do{ asm volatile("s_waitcnt lgkmcnt(2)" ::: "memory"); __builtin_amdgcn_sched_barrier(0); }while(0)
#define LGKM0 do{ asm volatile("s_waitcnt lgkmcnt(0)" ::: "memory"); __builtin_amdgcn_sched_barrier(0); }while(0)

__global__ __launch_bounds__(512, 2) void lstm_core(
    const float* __restrict__ Whh,    // [2,512,128]
    const float* __restrict__ Wih,    // [2,512,128]
    float* __restrict__ ws)
{
    __shared__ float xsT[8192];                       // [512 t][16 seq]
    __shared__ __align__(16) uint16_t h0s[2*H0ELE];   // h0^T double buf
    __shared__ __align__(16) uint16_t h1s[2*H1ELE];   // h1^T double buf

    const int tid = threadIdx.x;
    const int wv = tid>>6, l = tid&63;
    const int q4 = (l>>4)<<2;
    const int seq = l&15;
    const int bx = blockIdx.x, n0 = bx*16;

    for (int i=tid;i<8192;i+=512) xsT[i] = ws[OFF_XST + bx*8192 + i];
    for (int i=tid;i<2*H0ELE;i+=512) h0s[i]=0;
    for (int i=tid;i<2*H1ELE;i+=512) h1s[i]=0;
    __syncthreads();   // <-- race fix: zero-fill fully visible before special rows
    if (tid<16){
        h0s[129*16+tid]=0x3F80; h0s[H0ELE+129*16+tid]=0x3F80;   // constant-1 row, both bufs
        h0s[128*16+tid] = (uint16_t)packbf2(ws[OFF_XST + bx*8192 + tid], 0.f); // xs_0
    }

    // ---- resident weights (bf16 frags, gate order g'=4u+type) ----
    bf16x8 wL0[4][5], wI1[4][4], wH1[4][4];
    uint32_t b1pk[4][2];
    #pragma unroll
    for (int mt=0;mt<4;++mt){
        int gp  = (wv*4+mt)*16 + seq;        // A-operand row (M = l&15)
        int row = (gp&3)*128 + (gp>>2);      // orig gate row: type*128 + unit
        const float* p0 = Whh + row*128;
        const float* p1 = Wih + 65536 + row*128;
        const float* p2 = Whh + 65536 + row*128;
        #pragma unroll
        for (int kk=0;kk<4;++kk){
            wL0[mt][kk] = load_frag(p0, kk*32+q4);
            wI1[mt][kk] = load_frag(p1, kk*32+q4);
            wH1[mt][kk] = load_frag(p2, kk*32+q4);
        }
        FragU au; au.u4[0]=au.u4[1]=au.u4[2]=au.u4[3]=0;
        if (q4==0) au.u4[0] = packbf2(ws[OFF_A+row], ws[OFF_B0+row]);  // aug: k=128 -> A', k=129 -> B0'
        wL0[mt][4] = au.v;
        int uu = (wv*4+mt)*4 + (l>>4);       // D-layout unit index
        b1pk[mt][0] = packbf2(ws[OFF_B1+uu],     ws[OFF_B1+128+uu]);
        b1pk[mt][1] = packbf2(ws[OFF_B1+256+uu], ws[OFF_B1+384+uu]);
    }

    float c0[4]={0,0,0,0}, c1[4]={0,0,0,0};
    const unsigned trh0 = (unsigned)(uintptr_t)(&h0s[0]) + (unsigned)l*8u;
    const unsigned trh1 = (unsigned)(uintptr_t)(&h1s[0]) + (unsigned)l*8u;

    __syncthreads();

    for (int t=0;t<512;++t){
        const int cur = t&1;
        const unsigned h0r = trh0 + (unsigned)cur*(H0ELE*2);
        const unsigned h0n = trh0 + (unsigned)(cur^1)*(H0ELE*2);
        const unsigned h1r = trh1 + (unsigned)cur*(H1ELE*2);
        const int wo0 = (cur^1)*H0ELE;
        const int wo1 = (cur^1)*H1ELE;

        // ================= phase 1: layer 0 =================
        f32x4 acc0={0,0,0,0}, acc1={0,0,0,0}, acc2={0,0,0,0}, acc3={0,0,0,0};
        {
            uint2v ra, rb, pa, pb;
            TRD(ra, h0r, 0); TRD2(rb, h0r, 0);
            #pragma unroll
            for (int kk=0;kk<5;++kk){
                if (kk<4){ TRD(pa, h0r, (kk+1)*1024); TRD2(pb, h0r, (kk+1)*1024); LGKM2; }
                else     { LGKM0; }
                FragU f; f.p[0]=ra; f.p[1]=rb;
                acc0 = mm(wL0[0][kk], f.v, acc0);
                acc1 = mm(wL0[1][kk], f.v, acc1);
                acc2 = mm(wL0[2][kk], f.v, acc2);
                acc3 = mm(wL0[3][kk], f.v, acc3);
                ra=pa; rb=pb;
            }
        }
        #pragma unroll
        for (int mt=0;mt<4;++mt){
            f32x4 a = (mt==0)?acc0:(mt==1)?acc1:(mt==2)?acc2:acc3;
            float i_ = sigf(a[0]);
            float f_ = sigf(a[1]);
            float g_ = tanh_fast(a[2]);
            float o_ = sigf(a[3]);
            float cn = f_*c0[mt] + i_*g_;
            c0[mt] = cn;
            float h = o_*tanh_fast(cn);
            int uu = (wv*4+mt)*4 + (l>>4);
            h0s[wo0 + uu*16 + seq] = (uint16_t)packbf2(h, 0.f);
        }
        if (wv==0 && l<16){
            int tn = (t<511)? t+1 : 0;
            h0s[wo0 + 128*16 + l] = (uint16_t)packbf2(xsT[tn*16+l], 0.f);  // xs for next step
        }
        __syncthreads();

        // ================= phase 2: layer 1 (K = h0 new | h1 cur) =================
        acc0=(f32x4){0,0,0,0}; acc1=(f32x4){0,0,0,0}; acc2=(f32x4){0,0,0,0}; acc3=(f32x4){0,0,0,0};
        {
            uint2v ra, rb, pa, pb;
            TRD(ra, h0n, 0); TRD2(rb, h0n, 0);
            #pragma unroll
            for (int kk=0;kk<8;++kk){
                if (kk<7){
                    unsigned nb = (kk<3)? (h0n+(unsigned)(kk+1)*1024u) : (h1r+(unsigned)(kk-3)*1024u);
                    TRD(pa, nb, 0); TRD2(pb, nb, 0); LGKM2;
                } else { LGKM0; }
                FragU f; f.p[0]=ra; f.p[1]=rb;
                if (kk<4){
                    acc0 = mm(wI1[0][kk], f.v, acc0);
                    acc1 = mm(wI1[1][kk], f.v, acc1);
                    acc2 = mm(wI1[2][kk], f.v, acc2);
                    acc3 = mm(wI1[3][kk], f.v, acc3);
                } else {
                    acc0 = mm(wH1[0][kk-4], f.v, acc0);
                    acc1 = mm(wH1[1][kk-4], f.v, acc1);
                    acc2 = mm(wH1[2][kk-4], f.v, acc2);
                    acc3 = mm(wH1[3][kk-4], f.v, acc3);
                }
                ra=pa; rb=pb;
            }
        }
        #pragma unroll
        for (int mt=0;mt<4;++mt){
            f32x4 a = (mt==0)?acc0:(mt==1)?acc1:(mt==2)?acc2:acc3;
            float i_ = sigf(a[0] + bflo(b1pk[mt][0]));
            float f_ = sigf(a[1] + bfhi(b1pk[mt][0]));
            float g_ = tanh_fast(a[2] + bflo(b1pk[mt][1]));
            float o_ = sigf(a[3] + bfhi(b1pk[mt][1]));
            float cn = f_*c1[mt] + i_*g_;
            c1[mt] = cn;
            float h = o_*tanh_fast(cn);
            int uu = (wv*4+mt)*4 + (l>>4);
            h1s[wo1 + uu*16 + seq] = (uint16_t)packbf2(h, 0.f);
            if (t==511) ws[OFF_H1 + (n0+seq)*128 + uu] = h;
        }
        __syncthreads();
    }
}

// ---------------- K5: FC head + de-normalization ----------------
__global__ void out_k(const float* __restrict__ fcW, const float* __restrict__ fcb,
                      const float* __restrict__ ws, float* __restrict__ out){
    __shared__ float hl[128];
    int n = blockIdx.x, tid = threadIdx.x;    // block=128
    hl[tid] = ws[OFF_H1 + n*128 + tid];
    __syncthreads();
    if (tid < PREDN){
        float acc = fcb[tid];
        const float* wr = fcW + tid*128;
        #pragma unroll 4
        for (int k=0;k<128;k++) acc += wr[k]*hl[k];
        int idx = n*PREDN + tid;
        int b = idx / 672, u = idx % 7;
        out[idx] = acc * ws[OFF_STD + b*7 + u] + ws[OFF_MEAN + b*7 + u];
    }
}

extern "C" void kernel_launch(void* const* d_in, const int* in_sizes, int n_in,
                              void* d_out, int out_size, void* d_ws, size_t ws_size,
                              hipStream_t stream)
{
    const float* x    = (const float*)d_in[0];
    const float* embW = (const float*)d_in[1];
    const float* embb = (const float*)d_in[2];
    const float* Wih  = (const float*)d_in[3];
    const float* Whh  = (const float*)d_in[4];
    const float* bih  = (const float*)d_in[5];
    const float* bhh  = (const float*)d_in[6];
    const float* fcW  = (const float*)d_in[7];
    const float* fcb  = (const float*)d_in[8];
    float* ws  = (float*)d_ws;
    float* out = (float*)d_out;

    stats_k<<<448, 64, 0, stream>>>(x, ws);
    norm_k<<<896, 256, 0, stream>>>(x, ws);
    prep_k<<<1, 512, 0, stream>>>(Wih, embW, embb, bih, bhh, ws);
    lstm_core<<<28, 512, 0, stream>>>(Whh, Wih, ws);
    out_k<<<NN, 128, 0, stream>>>(fcW, fcb, ws, out);
}

// Round 4
// 1957.629 us; speedup vs baseline: 2.0498x; 1.0252x over previous
//
#include <hip/hip_runtime.h>
#include <stdint.h>

typedef short bf16x8 __attribute__((ext_vector_type(8)));
typedef float f32x4  __attribute__((ext_vector_type(4)));
typedef unsigned int uint2v __attribute__((ext_vector_type(2)));

#define HH 128
#define NN 448
#define PREDN 96

// ws layout (float offsets). Total 280,960 floats = 1.124 MB (< proven 1.157 MB).
#define OFF_MEAN 0
#define OFF_STD  448
#define OFF_A    896
#define OFF_B0   1408
#define OFF_B1   1920
#define OFF_H1   2432        // 448*128 floats
#define OFF_XSB  59776       // bf16 xs transposed: 28 blk * 512 t * 16 seq u16 (114688 floats)
#define OFF_WPK  174464      // packed weight frags: 32 wvmt * 13 slots * 64 lanes * uint4 (106496 floats)

__device__ __forceinline__ float bflo(uint32_t w){ union{uint32_t u; float f;} v; v.u = w<<16; return v.f; }
__device__ __forceinline__ float bfhi(uint32_t w){ union{uint32_t u; float f;} v; v.u = w & 0xffff0000u; return v.f; }

static __device__ __forceinline__ uint32_t packbf2(float a, float b){
    union { float f; uint32_t u; } ua, ub; ua.f = a; ub.f = b;
    uint32_t x = ua.u, y = ub.u;
    uint32_t lo = (x + 0x7fffu + ((x>>16)&1u)) >> 16;
    uint32_t hi = (y + 0x7fffu + ((y>>16)&1u)) >> 16;
    return (lo & 0xffffu) | (hi<<16);
}

__device__ __forceinline__ float sigf(float x){
    return __fdividef(1.f, 1.f + __expf(-x));
}
__device__ __forceinline__ float tanh_fast(float x){
    float e = __expf(2.f*x);
    return 1.f - __fdividef(2.f, e + 1.f);
}

// ---------------- K1: per-(b,u) mean/std over time ----------------
__global__ void stats_k(const float* __restrict__ x, float* __restrict__ ws){
    int bu = blockIdx.x;            // 0..447
    int b = bu / 7, u = bu % 7;
    int i = threadIdx.x;            // one wave
    const float* p = x + b*3584 + u;
    float s = 0.f, q = 0.f;
    #pragma unroll
    for (int m=0;m<8;m++){ float v = p[(i + 64*m)*7]; s += v; q += v*v; }
    for (int o=32;o>0;o>>=1){ s += __shfl_down(s,o); q += __shfl_down(q,o); }
    if (i==0){
        float mean = s * (1.f/512.f);
        float var  = q * (1.f/512.f) - mean*mean;
        ws[OFF_MEAN + bu] = mean;
        ws[OFF_STD  + bu] = sqrtf(var + 1e-5f);
    }
}

// ---------------- K2: normalize + write transposed bf16 [blk][t][16] ----------------
__global__ void norm_k(const float* __restrict__ x, float* __restrict__ ws){
    int i = blockIdx.x*256 + threadIdx.x;   // < 229376 exactly
    int b = i / 3584, u = i % 7;            // 3584 % 7 == 0
    float m = ws[OFF_MEAN + b*7 + u];
    float sd = ws[OFF_STD + b*7 + u];
    float v = (x[i] - m) / sd;
    int np = i >> 9, tp = i & 511;          // raw-reshape row/col
    uint16_t* xb = (uint16_t*)(ws + OFF_XSB);
    xb[(np>>4)*8192 + tp*16 + (np&15)] = (uint16_t)(packbf2(v, 0.f) & 0xffffu);
}

// ---------------- K3: A' = Wih0@embW, B0', B1' (orig gate order) ----------------
__global__ void prep_k(const float* __restrict__ Wih, const float* __restrict__ embW,
                       const float* __restrict__ embb, const float* __restrict__ bih,
                       const float* __restrict__ bhh, float* __restrict__ ws){
    int g = threadIdx.x;            // 0..511
    const float* wr = Wih + g*HH;
    float a = 0.f, bb = 0.f;
    #pragma unroll 4
    for (int k=0;k<HH;k++){ a += wr[k]*embW[k]; bb += wr[k]*embb[k]; }
    ws[OFF_A  + g] = a;
    ws[OFF_B0 + g] = bb + bih[g] + bhh[g];
    ws[OFF_B1 + g] = bih[512 + g] + bhh[512 + g];
}

// ---------------- K3b: pre-pack weight MFMA fragments (bf16, frag-linear) ----------
// slot 0..3 = Whh L0 kk0..3, slot 4 = aug (A',B0'), slot 5..8 = Wih L1, 9..12 = Whh L1
__global__ void prep2_k(const float* __restrict__ Whh, const float* __restrict__ Wih,
                        float* __restrict__ ws){
    int idx = blockIdx.x*256 + threadIdx.x;   // 0..26623
    int lane = idx & 63;
    int sg = idx >> 6;                        // 0..415
    int wvmt = sg / 13, slot = sg % 13;
    int gp  = wvmt*16 + (lane&15);
    int row = (gp&3)*128 + (gp>>2);
    int kq  = (lane>>4)<<2;
    uint4 r;
    if (slot == 4){
        r.x = r.y = r.z = r.w = 0u;
        if (kq == 0) r.x = packbf2(ws[OFF_A+row], ws[OFF_B0+row]);
    } else {
        const float* src; int kk;
        if (slot < 4)      { src = Whh + row*128;         kk = slot;   }
        else if (slot < 9) { src = Wih + 65536 + row*128; kk = slot-5; }
        else               { src = Whh + 65536 + row*128; kk = slot-9; }
        int k0 = kk*32 + kq;
        r.x = packbf2(src[k0],    src[k0+1]);
        r.y = packbf2(src[k0+2],  src[k0+3]);
        r.z = packbf2(src[k0+16], src[k0+17]);
        r.w = packbf2(src[k0+18], src[k0+19]);
    }
    ((uint4*)(ws + OFF_WPK))[sg*64 + lane] = r;
}

// ---------------- K4: persistent MFMA LSTM, 28 blocks x 16 seq ----------------
#define H0ROWS 160
#define H0ELE (H0ROWS*16)   // 2560 elems per buffer
#define H1ELE (128*16)      // 2048

union FragU { bf16x8 v; uint2v p[2]; uint32_t u4[4]; uint4 q; };

__device__ __forceinline__ f32x4 mm(bf16x8 a, bf16x8 b, f32x4 c){
    return __builtin_amdgcn_mfma_f32_16x16x32_bf16(a, b, c, 0, 0, 0);
}

#define TRD(d, b, off)  asm volatile("ds_read_b64_tr_b16 %0, %1" : "=v"(d) : "v"((unsigned)((b)+(off))))
#define TRD2(d, b, off) asm volatile("ds_read_b64_tr_b16 %0, %1 offset:512" : "=v"(d) : "v"((unsigned)((b)+(off))))
#define LGKM4 do{ asm volatile("s_waitcnt lgkmcnt(4)" ::: "memory"); __builtin_amdgcn_sched_barrier(0); }while(0)
#define LGKM2 do{ asm volatile("s_waitcnt lgkmcnt(2)" ::: "memory"); __builtin_amdgcn_sched_barrier(0); }while(0)
#define LGKM0 do{ asm volatile("s_waitcnt lgkmcnt(0)" ::: "memory"); __builtin_amdgcn_sched_barrier(0); }while(0)

#define MFMA4(W, J, A_, B_) do{ FragU f_; f_.p[0]=(A_); f_.p[1]=(B_); \
    acc0 = mm(W[0][J], f_.v, acc0); acc1 = mm(W[1][J], f_.v, acc1);   \
    acc2 = mm(W[2][J], f_.v, acc2); acc3 = mm(W[3][J], f_.v, acc3); }while(0)

__global__ __launch_bounds__(512, 2) void lstm_core(float* __restrict__ ws)
{
    __shared__ uint16_t xsT[8192];                    // bf16 [512 t][16 seq]
    __shared__ __align__(16) uint16_t h0s[2*H0ELE];   // h0^T double buf (rows 128=xs,129=1,130..159=0)
    __shared__ __align__(16) uint16_t h1s[2*H1ELE];   // h1^T double buf

    const int tid = threadIdx.x;
    const int wv = tid>>6, l = tid&63;
    const int seq = l&15;
    const int bx = blockIdx.x, n0 = bx*16;

    const uint16_t* xb = (const uint16_t*)(ws + OFF_XSB) + bx*8192;
    for (int i=tid;i<8192;i+=512) xsT[i] = xb[i];
    for (int i=tid;i<2*H0ELE;i+=512) h0s[i]=0;
    for (int i=tid;i<2*H1ELE;i+=512) h1s[i]=0;
    __syncthreads();   // zero-fill fully visible before special rows
    if (tid<16){
        h0s[129*16+tid]=0x3F80; h0s[H0ELE+129*16+tid]=0x3F80;   // constant-1 row, both bufs
        h0s[128*16+tid] = xsT[tid];                              // xs_0
    }

    // ---- resident weights: pre-packed bf16 frags (16B vector loads, no repack VALU) ----
    bf16x8 wL0[4][5], wI1[4][4], wH1[4][4];
    uint32_t b1pk[4][2];
    const uint4* wpk = (const uint4*)(ws + OFF_WPK);
    #pragma unroll
    for (int mt=0;mt<4;++mt){
        int base = ((wv*4+mt)*13)*64 + l;
        #pragma unroll
        for (int kk=0;kk<5;kk++){ FragU u; u.q = wpk[base + kk*64];     wL0[mt][kk]=u.v; }
        #pragma unroll
        for (int kk=0;kk<4;kk++){ FragU u; u.q = wpk[base + (5+kk)*64]; wI1[mt][kk]=u.v; }
        #pragma unroll
        for (int kk=0;kk<4;kk++){ FragU u; u.q = wpk[base + (9+kk)*64]; wH1[mt][kk]=u.v; }
        int uu = (wv*4+mt)*4 + (l>>4);       // D-layout unit index
        b1pk[mt][0] = packbf2(ws[OFF_B1+uu],     ws[OFF_B1+128+uu]);
        b1pk[mt][1] = packbf2(ws[OFF_B1+256+uu], ws[OFF_B1+384+uu]);
    }

    float c0[4]={0,0,0,0}, c1[4]={0,0,0,0};
    const unsigned trh0 = (unsigned)(uintptr_t)(&h0s[0]) + (unsigned)l*8u;
    const unsigned trh1 = (unsigned)(uintptr_t)(&h1s[0]) + (unsigned)l*8u;

    __syncthreads();

    for (int t=0;t<512;++t){
        const int cur = t&1;
        const unsigned h0r = trh0 + (unsigned)cur*(H0ELE*2);
        const unsigned h0n = trh0 + (unsigned)(cur^1)*(H0ELE*2);
        const unsigned h1r = trh1 + (unsigned)cur*(H1ELE*2);
        const int wo0 = (cur^1)*H0ELE;
        const int wo1 = (cur^1)*H1ELE;

        // ================= phase 1: layer 0 (K = 5 frags, depth-3 prefetch) =================
        f32x4 acc0={0,0,0,0}, acc1={0,0,0,0}, acc2={0,0,0,0}, acc3={0,0,0,0};
        {
            uint2v a0,b0,a1,b1,a2,b2,a3,b3,a4,b4;
            TRD(a0,h0r,0);    TRD2(b0,h0r,0);
            TRD(a1,h0r,1024); TRD2(b1,h0r,1024);
            TRD(a2,h0r,2048); TRD2(b2,h0r,2048);
            LGKM4; TRD(a3,h0r,3072); TRD2(b3,h0r,3072); MFMA4(wL0,0,a0,b0);
            LGKM4; TRD(a4,h0r,4096); TRD2(b4,h0r,4096); MFMA4(wL0,1,a1,b1);
            LGKM4; MFMA4(wL0,2,a2,b2);
            LGKM2; MFMA4(wL0,3,a3,b3);
            LGKM0; MFMA4(wL0,4,a4,b4);
        }
        #pragma unroll
        for (int mt=0;mt<4;++mt){
            f32x4 a = (mt==0)?acc0:(mt==1)?acc1:(mt==2)?acc2:acc3;
            float i_ = sigf(a[0]);
            float f_ = sigf(a[1]);
            float g_ = tanh_fast(a[2]);
            float o_ = sigf(a[3]);
            float cn = f_*c0[mt] + i_*g_;
            c0[mt] = cn;
            float h = o_*tanh_fast(cn);
            int uu = (wv*4+mt)*4 + (l>>4);
            h0s[wo0 + uu*16 + seq] = (uint16_t)packbf2(h, 0.f);
        }
        if (wv==0 && l<16){
            int tn = (t<511)? t+1 : 0;
            h0s[wo0 + 128*16 + l] = xsT[tn*16+l];   // bf16 xs for next step
        }
        __syncthreads();

        // ================= phase 2: layer 1 (K = h0 new | h1 cur, 8 frags) =================
        acc0=(f32x4){0,0,0,0}; acc1=(f32x4){0,0,0,0}; acc2=(f32x4){0,0,0,0}; acc3=(f32x4){0,0,0,0};
        {
            uint2v a0,b0,a1,b1,a2,b2,a3,b3,a4,b4,a5,b5,a6,b6,a7,b7;
            TRD(a0,h0n,0);    TRD2(b0,h0n,0);
            TRD(a1,h0n,1024); TRD2(b1,h0n,1024);
            TRD(a2,h0n,2048); TRD2(b2,h0n,2048);
            LGKM4; TRD(a3,h0n,3072); TRD2(b3,h0n,3072); MFMA4(wI1,0,a0,b0);
            LGKM4; TRD(a4,h1r,0);    TRD2(b4,h1r,0);    MFMA4(wI1,1,a1,b1);
            LGKM4; TRD(a5,h1r,1024); TRD2(b5,h1r,1024); MFMA4(wI1,2,a2,b2);
            LGKM4; TRD(a6,h1r,2048); TRD2(b6,h1r,2048); MFMA4(wI1,3,a3,b3);
            LGKM4; TRD(a7,h1r,3072); TRD2(b7,h1r,3072); MFMA4(wH1,0,a4,b4);
            LGKM4; MFMA4(wH1,1,a5,b5);
            LGKM2; MFMA4(wH1,2,a6,b6);
            LGKM0; MFMA4(wH1,3,a7,b7);
        }
        #pragma unroll
        for (int mt=0;mt<4;++mt){
            f32x4 a = (mt==0)?acc0:(mt==1)?acc1:(mt==2)?acc2:acc3;
            float i_ = sigf(a[0] + bflo(b1pk[mt][0]));
            float f_ = sigf(a[1] + bfhi(b1pk[mt][0]));
            float g_ = tanh_fast(a[2] + bflo(b1pk[mt][1]));
            float o_ = sigf(a[3] + bfhi(b1pk[mt][1]));
            float cn = f_*c1[mt] + i_*g_;
            c1[mt] = cn;
            float h = o_*tanh_fast(cn);
            int uu = (wv*4+mt)*4 + (l>>4);
            h1s[wo1 + uu*16 + seq] = (uint16_t)packbf2(h, 0.f);
            if (t==511) ws[OFF_H1 + (n0+seq)*128 + uu] = h;
        }
        __syncthreads();
    }
}

// ---------------- K5: FC head + de-normalization ----------------
__global__ void out_k(const float* __restrict__ fcW, const float* __restrict__ fcb,
                      const float* __restrict__ ws, float* __restrict__ out){
    __shared__ float hl[128];
    int n = blockIdx.x, tid = threadIdx.x;    // block=128
    hl[tid] = ws[OFF_H1 + n*128 + tid];
    __syncthreads();
    if (tid < PREDN){
        float acc = fcb[tid];
        const float* wr = fcW + tid*128;
        #pragma unroll 4
        for (int k=0;k<128;k++) acc += wr[k]*hl[k];
        int idx = n*PREDN + tid;
        int b = idx / 672, u = idx % 7;
        out[idx] = acc * ws[OFF_STD + b*7 + u] + ws[OFF_MEAN + b*7 + u];
    }
}

extern "C" void kernel_launch(void* const* d_in, const int* in_sizes, int n_in,
                              void* d_out, int out_size, void* d_ws, size_t ws_size,
                              hipStream_t stream)
{
    const float* x    = (const float*)d_in[0];
    const float* embW = (const float*)d_in[1];
    const float* embb = (const float*)d_in[2];
    const float* Wih  = (const float*)d_in[3];
    const float* Whh  = (const float*)d_in[4];
    const float* bih  = (const float*)d_in[5];
    const float* bhh  = (const float*)d_in[6];
    const float* fcW  = (const float*)d_in[7];
    const float* fcb  = (const float*)d_in[8];
    float* ws  = (float*)d_ws;
    float* out = (float*)d_out;

    stats_k<<<448, 64, 0, stream>>>(x, ws);
    norm_k<<<896, 256, 0, stream>>>(x, ws);
    prep_k<<<1, 512, 0, stream>>>(Wih, embW, embb, bih, bhh, ws);
    prep2_k<<<104, 256, 0, stream>>>(Whh, Wih, ws);
    lstm_core<<<28, 512, 0, stream>>>(ws);
    out_k<<<NN, 128, 0, stream>>>(fcW, fcb, ws, out);
}

// Round 5
// 1002.572 us; speedup vs baseline: 4.0025x; 1.9526x over previous
//
#include <hip/hip_runtime.h>
#include <stdint.h>

typedef short bf16x8 __attribute__((ext_vector_type(8)));
typedef float f32x4  __attribute__((ext_vector_type(4)));

#define HH 128
#define NN 448
#define PREDN 96

// ws layout (float offsets)
#define OFF_MEAN 0
#define OFF_STD  448
#define OFF_A    896
#define OFF_B0   1408
#define OFF_B1   1920
#define OFF_H1   2432        // 448*128 floats
#define OFF_XSB  59776       // bf16 xs transposed: 28 blk * 512 t * 16 seq u16
#define OFF_WPK  174464      // packed weight frags: 32 wvmt * 13 slots * 64 lanes * uint4

#define L2E  1.442695041f
#define L2E2 2.885390082f

// h layout: per buffer [16 seq][296 k] bf16, row stride 592 B.
// 592/4 = 148 dwords, 148 % 32 = 20 -> rows 0..7 hit distinct bank groups, 2-way overall (free).
// k: 0..127 = h0, 128..255 = h1, 256 = xs, 257 = 1, 258..295 = zero pad.
#define ROWB 592
#define BUFB 9472            // bytes per buffer (16*592); two buffers total

__device__ __forceinline__ float bflo(uint32_t w){ union{uint32_t u; float f;} v; v.u = w<<16; return v.f; }
__device__ __forceinline__ float bfhi(uint32_t w){ union{uint32_t u; float f;} v; v.u = w & 0xffff0000u; return v.f; }

static __device__ __forceinline__ uint32_t packbf2(float a, float b){
    union { float f; uint32_t u; } ua, ub; ua.f = a; ub.f = b;
    uint32_t x = ua.u, y = ub.u;
    uint32_t lo = (x + 0x7fffu + ((x>>16)&1u)) >> 16;
    uint32_t hi = (y + 0x7fffu + ((y>>16)&1u)) >> 16;
    return (lo & 0xffffu) | (hi<<16);
}
static __device__ __forceinline__ uint16_t bfr(float f){
    union { float f; uint32_t u; } v; v.f = f;
    return (uint16_t)((v.u + 0x7fffu + ((v.u>>16)&1u)) >> 16);
}

#if __has_builtin(__builtin_amdgcn_exp2f)
#define EXP2(x) __builtin_amdgcn_exp2f(x)
#else
#define EXP2(x) __expf(0.69314718056f*(x))
#endif
#if __has_builtin(__builtin_amdgcn_rcpf)
#define RCPF(x) __builtin_amdgcn_rcpf(x)
#else
#define RCPF(x) (1.0f/(x))
#endif

// preacts pre-scaled by log2e (sigmoid gates) / 2*log2e (tanh gate)
__device__ __forceinline__ float sig2(float x){ return RCPF(1.f + EXP2(-x)); }
__device__ __forceinline__ float tanh2(float xs){ return fmaf(-2.f, RCPF(EXP2(xs) + 1.f), 1.f); }

// ---------------- K1: per-(b,u) mean/std over time ----------------
__global__ void stats_k(const float* __restrict__ x, float* __restrict__ ws){
    int bu = blockIdx.x;
    int b = bu / 7, u = bu % 7;
    int i = threadIdx.x;
    const float* p = x + b*3584 + u;
    float s = 0.f, q = 0.f;
    #pragma unroll
    for (int m=0;m<8;m++){ float v = p[(i + 64*m)*7]; s += v; q += v*v; }
    for (int o=32;o>0;o>>=1){ s += __shfl_down(s,o); q += __shfl_down(q,o); }
    if (i==0){
        float mean = s * (1.f/512.f);
        float var  = q * (1.f/512.f) - mean*mean;
        ws[OFF_MEAN + bu] = mean;
        ws[OFF_STD  + bu] = sqrtf(var + 1e-5f);
    }
}

// ---------------- K2: normalize + write transposed bf16 [blk][t][16] ----------------
__global__ void norm_k(const float* __restrict__ x, float* __restrict__ ws){
    int i = blockIdx.x*256 + threadIdx.x;   // < 229376 exactly
    int b = i / 3584, u = i % 7;
    float m = ws[OFF_MEAN + b*7 + u];
    float sd = ws[OFF_STD + b*7 + u];
    float v = (x[i] - m) / sd;
    int np = i >> 9, tp = i & 511;          // raw-reshape row/col
    uint16_t* xb = (uint16_t*)(ws + OFF_XSB);
    xb[(np>>4)*8192 + tp*16 + (np&15)] = (uint16_t)(packbf2(v, 0.f) & 0xffffu);
}

// ---------------- K3: A' = Wih0@embW, B0', B1' (raw; scaled at pack time) ------------
__global__ void prep_k(const float* __restrict__ Wih, const float* __restrict__ embW,
                       const float* __restrict__ embb, const float* __restrict__ bih,
                       const float* __restrict__ bhh, float* __restrict__ ws){
    int g = threadIdx.x;
    const float* wr = Wih + g*HH;
    float a = 0.f, bb = 0.f;
    #pragma unroll 4
    for (int k=0;k<HH;k++){ a += wr[k]*embW[k]; bb += wr[k]*embb[k]; }
    ws[OFF_A  + g] = a;
    ws[OFF_B0 + g] = bb + bih[g] + bhh[g];
    ws[OFF_B1 + g] = bih[512 + g] + bhh[512 + g];
}

// ---------------- K3b: pre-pack weight frags (bf16, consecutive-k, pre-scaled) --------
// slot 0..3 = Whh L0, slot 4 = aug (A',B0'), slot 5..8 = Wih L1, 9..12 = Whh L1
__global__ void prep2_k(const float* __restrict__ Whh, const float* __restrict__ Wih,
                        float* __restrict__ ws){
    int idx = blockIdx.x*256 + threadIdx.x;   // 0..26623
    int lane = idx & 63;
    int sg = idx >> 6;                        // 0..415
    int wvmt = sg / 13, slot = sg % 13;
    int gp  = wvmt*16 + (lane&15);
    int type = gp & 3, unit = gp >> 2;
    int row = type*128 + unit;
    float S = (type==2) ? L2E2 : L2E;
    uint4 r;
    if (slot == 4){
        r.x = r.y = r.z = r.w = 0u;
        if ((lane>>4) == 0) r.x = packbf2(ws[OFF_A+row]*S, ws[OFF_B0+row]*S);
    } else {
        const float* src; int kk;
        if (slot < 4)      { src = Whh + row*128;         kk = slot;   }
        else if (slot < 9) { src = Wih + 65536 + row*128; kk = slot-5; }
        else               { src = Whh + 65536 + row*128; kk = slot-9; }
        int k0 = kk*32 + (lane>>4)*8;
        r.x = packbf2(src[k0]*S,   src[k0+1]*S);
        r.y = packbf2(src[k0+2]*S, src[k0+3]*S);
        r.z = packbf2(src[k0+4]*S, src[k0+5]*S);
        r.w = packbf2(src[k0+6]*S, src[k0+7]*S);
    }
    ((uint4*)(ws + OFF_WPK))[sg*64 + lane] = r;
}

// ---------------- K4: persistent MFMA LSTM, 28 blocks x 16 seq ----------------
union FragU { bf16x8 v; uint4 q; };

__device__ __forceinline__ f32x4 mm(bf16x8 a, bf16x8 b, f32x4 c){
    return __builtin_amdgcn_mfma_f32_16x16x32_bf16(a, b, c, 0, 0, 0);
}
#define LD(p) (*(const bf16x8*)(p))

__global__ __launch_bounds__(512, 2) void lstm_core(float* __restrict__ ws)
{
    __shared__ uint16_t xsT[8192];                      // bf16 [512 t][16 seq]
    __shared__ __align__(16) uint16_t hbuf[2*BUFB/2];   // 2 buffers, BUFB bytes each

    const int tid = threadIdx.x;
    const int wv = tid>>6, l = tid&63;
    const int r   = l & 15;                 // seq within block (D col / B col)
    const int q16 = (l>>4)*16;              // k-subgroup byte offset
    const int bx = blockIdx.x, n0 = bx*16;
    char* hb = (char*)hbuf;

    const uint16_t* xb = (const uint16_t*)(ws + OFF_XSB) + bx*8192;
    for (int i=tid;i<8192;i+=512) xsT[i] = xb[i];
    for (int i=tid;i<BUFB;i+=512) hbuf[i] = 0;          // zero both buffers (BUFB u16 = 2*BUFB bytes)
    __syncthreads();    // zero-fill + xsT visible before special rows (R2 race lesson)
    if (tid < 32){
        int bsel = tid>>4, rr = tid&15;
        *(uint16_t*)(hb + bsel*BUFB + rr*ROWB + 514) = 0x3F80;   // k=257 const-1, both bufs
    }
    if (tid < 16){
        *(uint16_t*)(hb + tid*ROWB + 512) = xsT[tid];            // xs_0 at k=256, buf0
    }

    // ---- resident weights: pre-packed, pre-scaled bf16 frags ----
    bf16x8 wL0[4][5], wI1[4][4], wH1[4][4];
    uint32_t b1pk[4][2];
    const uint4* wpk = (const uint4*)(ws + OFF_WPK);
    #pragma unroll
    for (int mt=0;mt<4;++mt){
        int base = ((wv*4+mt)*13)*64 + l;
        #pragma unroll
        for (int kk=0;kk<5;kk++){ FragU u; u.q = wpk[base + kk*64];     wL0[mt][kk]=u.v; }
        #pragma unroll
        for (int kk=0;kk<4;kk++){ FragU u; u.q = wpk[base + (5+kk)*64]; wI1[mt][kk]=u.v; }
        #pragma unroll
        for (int kk=0;kk<4;kk++){ FragU u; u.q = wpk[base + (9+kk)*64]; wH1[mt][kk]=u.v; }
        int uu = (wv*4+mt)*4 + (l>>4);
        b1pk[mt][0] = packbf2(ws[OFF_B1+uu]*L2E,      ws[OFF_B1+128+uu]*L2E);
        b1pk[mt][1] = packbf2(ws[OFF_B1+256+uu]*L2E2, ws[OFF_B1+384+uu]*L2E);
    }

    float c0[4]={0,0,0,0}, c1[4]={0,0,0,0};
    const int rbase = r*ROWB + q16;                  // read base within a buffer
    const int wbase = r*ROWB + wv*32 + 2*(l>>4);     // write base (byte of 2*u); mt adds 8*mt

    __syncthreads();

    for (int t=0;t<512;++t){
        const int co = (t&1)*BUFB;
        const int no = BUFB - co;
        const char* pc = hb + co + rbase;
        const char* pn = hb + no + rbase;
        char* pw = hb + no + wbase;

        // ================= phase 1: layer 0 =================
        {
            bf16x8 f0 = LD(pc+0), f1 = LD(pc+64), f2 = LD(pc+128), f3 = LD(pc+192), fa = LD(pc+512);
            f32x4 a0={0,0,0,0}, a1={0,0,0,0}, a2={0,0,0,0}, a3={0,0,0,0};
            a0=mm(wL0[0][0],f0,a0); a1=mm(wL0[1][0],f0,a1); a2=mm(wL0[2][0],f0,a2); a3=mm(wL0[3][0],f0,a3);
            a0=mm(wL0[0][1],f1,a0); a1=mm(wL0[1][1],f1,a1); a2=mm(wL0[2][1],f1,a2); a3=mm(wL0[3][1],f1,a3);
            a0=mm(wL0[0][2],f2,a0); a1=mm(wL0[1][2],f2,a1); a2=mm(wL0[2][2],f2,a2); a3=mm(wL0[3][2],f2,a3);
            a0=mm(wL0[0][3],f3,a0); a1=mm(wL0[1][3],f3,a1); a2=mm(wL0[2][3],f3,a2); a3=mm(wL0[3][3],f3,a3);
            a0=mm(wL0[0][4],fa,a0); a1=mm(wL0[1][4],fa,a1); a2=mm(wL0[2][4],fa,a2); a3=mm(wL0[3][4],fa,a3);
            #pragma unroll
            for (int mt=0;mt<4;++mt){
                f32x4 a = (mt==0)?a0:(mt==1)?a1:(mt==2)?a2:a3;
                float i_ = sig2(a[0]);
                float f_ = sig2(a[1]);
                float g_ = tanh2(a[2]);
                float o_ = sig2(a[3]);
                float cn = fmaf(f_, c0[mt], i_*g_);
                c0[mt] = cn;
                float h = o_ * tanh2(cn*L2E2);
                *(uint16_t*)(pw + 8*mt) = bfr(h);
            }
        }
        __syncthreads();

        // ================= phase 2: layer 1 (K = h0 new | h1 cur) =================
        {
            bf16x8 g0 = LD(pn+0),   g1 = LD(pn+64),  g2 = LD(pn+128), g3 = LD(pn+192);
            bf16x8 v0 = LD(pc+256), v1 = LD(pc+320), v2 = LD(pc+384), v3 = LD(pc+448);
            f32x4 a0={0,0,0,0}, a1={0,0,0,0}, a2={0,0,0,0}, a3={0,0,0,0};
            a0=mm(wI1[0][0],g0,a0); a1=mm(wI1[1][0],g0,a1); a2=mm(wI1[2][0],g0,a2); a3=mm(wI1[3][0],g0,a3);
            a0=mm(wI1[0][1],g1,a0); a1=mm(wI1[1][1],g1,a1); a2=mm(wI1[2][1],g1,a2); a3=mm(wI1[3][1],g1,a3);
            a0=mm(wI1[0][2],g2,a0); a1=mm(wI1[1][2],g2,a1); a2=mm(wI1[2][2],g2,a2); a3=mm(wI1[3][2],g2,a3);
            a0=mm(wI1[0][3],g3,a0); a1=mm(wI1[1][3],g3,a1); a2=mm(wI1[2][3],g3,a2); a3=mm(wI1[3][3],g3,a3);
            a0=mm(wH1[0][0],v0,a0); a1=mm(wH1[1][0],v0,a1); a2=mm(wH1[2][0],v0,a2); a3=mm(wH1[3][0],v0,a3);
            a0=mm(wH1[0][1],v1,a0); a1=mm(wH1[1][1],v1,a1); a2=mm(wH1[2][1],v1,a2); a3=mm(wH1[3][1],v1,a3);
            a0=mm(wH1[0][2],v2,a0); a1=mm(wH1[1][2],v2,a1); a2=mm(wH1[2][2],v2,a2); a3=mm(wH1[3][2],v2,a3);
            a0=mm(wH1[0][3],v3,a0); a1=mm(wH1[1][3],v3,a1); a2=mm(wH1[2][3],v3,a2); a3=mm(wH1[3][3],v3,a3);
            #pragma unroll
            for (int mt=0;mt<4;++mt){
                f32x4 a = (mt==0)?a0:(mt==1)?a1:(mt==2)?a2:a3;
                float i_ = sig2(a[0] + bflo(b1pk[mt][0]));
                float f_ = sig2(a[1] + bfhi(b1pk[mt][0]));
                float g_ = tanh2(a[2] + bflo(b1pk[mt][1]));
                float o_ = sig2(a[3] + bfhi(b1pk[mt][1]));
                float cn = fmaf(f_, c1[mt], i_*g_);
                c1[mt] = cn;
                float h = o_ * tanh2(cn*L2E2);
                *(uint16_t*)(pw + 256 + 8*mt) = bfr(h);
                if (t==511) ws[OFF_H1 + (n0+r)*128 + (wv*16 + mt*4 + (l>>4))] = h;
            }
        }
        if (wv==0 && l<16){
            *(uint16_t*)(hb + no + l*ROWB + 512) = xsT[((t+1)&511)*16 + l];  // xs for next step
        }
        __syncthreads();
    }
}

// ---------------- K5: FC head + de-normalization ----------------
__global__ void out_k(const float* __restrict__ fcW, const float* __restrict__ fcb,
                      const float* __restrict__ ws, float* __restrict__ out){
    __shared__ float hl[128];
    int n = blockIdx.x, tid = threadIdx.x;
    hl[tid] = ws[OFF_H1 + n*128 + tid];
    __syncthreads();
    if (tid < PREDN){
        float acc = fcb[tid];
        const float* wr = fcW + tid*128;
        #pragma unroll 4
        for (int k=0;k<128;k++) acc += wr[k]*hl[k];
        int idx = n*PREDN + tid;
        int b = idx / 672, u = idx % 7;
        out[idx] = acc * ws[OFF_STD + b*7 + u] + ws[OFF_MEAN + b*7 + u];
    }
}

extern "C" void kernel_launch(void* const* d_in, const int* in_sizes, int n_in,
                              void* d_out, int out_size, void* d_ws, size_t ws_size,
                              hipStream_t stream)
{
    const float* x    = (const float*)d_in[0];
    const float* embW = (const float*)d_in[1];
    const float* embb = (const float*)d_in[2];
    const float* Wih  = (const float*)d_in[3];
    const float* Whh  = (const float*)d_in[4];
    const float* bih  = (const float*)d_in[5];
    const float* bhh  = (const float*)d_in[6];
    const float* fcW  = (const float*)d_in[7];
    const float* fcb  = (const float*)d_in[8];
    float* ws  = (float*)d_ws;
    float* out = (float*)d_out;

    stats_k<<<448, 64, 0, stream>>>(x, ws);
    norm_k<<<896, 256, 0, stream>>>(x, ws);
    prep_k<<<1, 512, 0, stream>>>(Wih, embW, embb, bih, bhh, ws);
    prep2_k<<<104, 256, 0, stream>>>(Whh, Wih, ws);
    lstm_core<<<28, 512, 0, stream>>>(ws);
    out_k<<<NN, 128, 0, stream>>>(fcW, fcb, ws, out);
}